// Round 1
// baseline (514.254 us; speedup 1.0000x reference)
//
#include <hip/hip_runtime.h>
#include <hip/hip_bf16.h>

#define N_NODES 2048
#define N_EDGES 4096
#define F_IN    256
#define H_HEADS 8
#define DHEAD   64
#define HD      512     // H_HEADS * DHEAD
#define SPLITS  4
#define NB      32      // nodes per block in main kernel

// ---------------------------------------------------------------------------
// Kernel 1: ht = X @ W  (both nodes@WN -> ht_n and edges@WE -> ht_e)
// 64x64 output tile per block, K staged in 32-chunks through LDS.
// ---------------------------------------------------------------------------
__global__ __launch_bounds__(256) void gemm_ht(
    const float* __restrict__ nodes, const float* __restrict__ edges,
    const float* __restrict__ WN, const float* __restrict__ WE,
    float* __restrict__ ht_n, float* __restrict__ ht_e)
{
  const int rt = blockIdx.x;   // 96 row tiles: 0..31 nodes, 32..95 edges
  const int ct = blockIdx.y;   // 8 col tiles
  const bool isNode = (rt < 32);
  const float* __restrict__ X = isNode ? nodes : edges;
  const float* __restrict__ W = isNode ? WN : WE;
  float* __restrict__ OUT     = isNode ? ht_n : ht_e;
  const int r0 = (isNode ? rt : rt - 32) * 64;

  __shared__ __align__(16) float Xs[32][68];  // [k][row], pad->16B-aligned rows
  __shared__ __align__(16) float Ws[32][64];  // [k][col]

  const int tid = threadIdx.x;
  const int tx = tid & 15, ty = tid >> 4;

  float acc[4][4];
#pragma unroll
  for (int i = 0; i < 4; ++i)
#pragma unroll
    for (int j = 0; j < 4; ++j) acc[i][j] = 0.f;

  for (int k0 = 0; k0 < F_IN; k0 += 32) {
    __syncthreads();
#pragma unroll
    for (int i = 0; i < 2; ++i) {
      int v = tid + i * 256;              // 0..511 float4 slots
      int r = v >> 3, kk = (v & 7) * 4;   // X: 64 rows x 8 float4
      float4 x = *(const float4*)&X[(size_t)(r0 + r) * F_IN + k0 + kk];
      Xs[kk + 0][r] = x.x; Xs[kk + 1][r] = x.y;
      Xs[kk + 2][r] = x.z; Xs[kk + 3][r] = x.w;
      int kw = v >> 4, cc = (v & 15) * 4; // W: 32 k-rows x 16 float4
      *(float4*)&Ws[kw][cc] =
          *(const float4*)&W[(size_t)(k0 + kw) * HD + ct * 64 + cc];
    }
    __syncthreads();
#pragma unroll
    for (int k = 0; k < 32; ++k) {
      float4 a4 = *(const float4*)&Xs[k][ty * 4];
      float4 b4 = *(const float4*)&Ws[k][tx * 4];
      float av[4] = {a4.x, a4.y, a4.z, a4.w};
      float bv[4] = {b4.x, b4.y, b4.z, b4.w};
#pragma unroll
      for (int i = 0; i < 4; ++i)
#pragma unroll
        for (int j = 0; j < 4; ++j)
          acc[i][j] = fmaf(av[i], bv[j], acc[i][j]);
    }
  }
#pragma unroll
  for (int i = 0; i < 4; ++i) {
    float4 o = make_float4(acc[i][0], acc[i][1], acc[i][2], acc[i][3]);
    *(float4*)&OUT[(size_t)(r0 + ty * 4 + i) * HD + ct * 64 + tx * 4] = o;
  }
}

// ---------------------------------------------------------------------------
// Kernel 2: score vectors. srcN[h,n]=ht_n[n,h,:].aN[h,:64]
//   tgtN[h,m]=ht_n[m,h,:].aN[h,64:], srcE[h,n]=ht_n[n,h,:].aE[h,:64],
//   tgtE[h,m]=ht_e[m,h,:].aE[h,64:].  One wave per dot, lane = d.
// ---------------------------------------------------------------------------
__global__ __launch_bounds__(256) void scores_kernel(
    const float* __restrict__ ht_n, const float* __restrict__ ht_e,
    const float* __restrict__ aN, const float* __restrict__ aE,
    float* __restrict__ srcN, float* __restrict__ tgtN,
    float* __restrict__ srcE, float* __restrict__ tgtE)
{
  int job = blockIdx.x * 4 + (threadIdx.x >> 6);
  int lane = threadIdx.x & 63;
  if (job >= 81920) return;
  const float* ht; const float* a; float* out; int h, r;
  if (job < 16384)      { int j = job;         h = j >> 11; r = j & 2047; ht = ht_n; a = aN + h * 128 + lane;      out = srcN + h * N_NODES + r; }
  else if (job < 32768) { int j = job - 16384; h = j >> 11; r = j & 2047; ht = ht_n; a = aN + h * 128 + 64 + lane; out = tgtN + h * N_NODES + r; }
  else if (job < 49152) { int j = job - 32768; h = j >> 11; r = j & 2047; ht = ht_n; a = aE + h * 128 + lane;      out = srcE + h * N_NODES + r; }
  else                  { int j = job - 49152; h = j >> 12; r = j & 4095; ht = ht_e; a = aE + h * 128 + 64 + lane; out = tgtE + h * N_EDGES + r; }
  float v = ht[(size_t)r * HD + h * 64 + lane] * (*a);
#pragma unroll
  for (int o = 32; o; o >>= 1) v += __shfl_xor(v, o);
  if (lane == 0) *out = v;
}

// ---------------------------------------------------------------------------
// Kernel 3: main GAT accumulation.
// Block = 32-node tile x m-split. 8 waves, wave h = head h.
// Phase 1 (lane=m): w = mask ? exp(lrelu(src+tgt)) : 0 -> LDS W tile, den.
// Phase 2 (lane=d): acc[n] += W[n][m] * ht[m][d], ht chunk in 64 VGPRs,
//                   W read as wave-uniform float4 broadcasts from LDS.
// ---------------------------------------------------------------------------
__device__ __forceinline__ void gat_part(
    const int* __restrict__ mat, int mat_stride,
    const float* __restrict__ tgt, int tgt_stride,
    const float* __restrict__ ht,
    const float* lds_src,            // [NB] for this head
    float (*lds_Wh)[64],             // [NB][64] region for this head
    int (*lds_mask)[64],             // [NB][64] shared by all waves
    int n0, int m_begin, int m_end, int h, int lane,
    float* __restrict__ NUM, float* __restrict__ DEN, int sh_idx)
{
  float acc[NB], den[NB];
#pragma unroll
  for (int n = 0; n < NB; ++n) { acc[n] = 0.f; den[n] = 0.f; }

  for (int m0 = m_begin; m0 < m_end; m0 += 64) {
    __syncthreads();   // all waves done reading previous mask tile
    {
      int t = threadIdx.x;
#pragma unroll
      for (int i = 0; i < 4; ++i) {
        int v = t + i * 512;  int r = v >> 6, c = v & 63;
        lds_mask[r][c] = mat[(size_t)(n0 + r) * mat_stride + m0 + c];
      }
    }
    __syncthreads();

    float tv = tgt[(size_t)h * tgt_stride + m0 + lane];
    float htreg[64];
#pragma unroll
    for (int j = 0; j < 64; ++j)
      htreg[j] = ht[(size_t)(m0 + j) * HD + h * 64 + lane];

#pragma unroll
    for (int n = 0; n < NB; ++n) {
      float e = lds_src[n] + tv;
      float sc = (e >= 0.f) ? e : 0.2f * e;
      float w = (lds_mask[n][lane] > 0) ? __expf(sc) : 0.f;
      den[n] += w;
      lds_Wh[n][lane] = w;
    }

#pragma unroll
    for (int n = 0; n < NB; ++n) {
      float a = acc[n];
      const float4* wrow = (const float4*)lds_Wh[n];
#pragma unroll
      for (int q = 0; q < 16; ++q) {
        float4 w4 = wrow[q];
        a = fmaf(w4.x, htreg[4 * q + 0], a);
        a = fmaf(w4.y, htreg[4 * q + 1], a);
        a = fmaf(w4.z, htreg[4 * q + 2], a);
        a = fmaf(w4.w, htreg[4 * q + 3], a);
      }
      acc[n] = a;
    }
  }

#pragma unroll
  for (int n = 0; n < NB; ++n) {
    float d = den[n];
#pragma unroll
    for (int o = 32; o; o >>= 1) d += __shfl_xor(d, o);
    if (lane == 0) DEN[(size_t)sh_idx * N_NODES + n0 + n] = d;
    NUM[((size_t)sh_idx * N_NODES + n0 + n) * 64 + lane] = acc[n];
  }
}

__global__ __launch_bounds__(512, 2) void gat_main(
    const float* __restrict__ ht_n, const float* __restrict__ ht_e,
    const float* __restrict__ srcN, const float* __restrict__ tgtN,
    const float* __restrict__ srcE, const float* __restrict__ tgtE,
    const int* __restrict__ matN, const int* __restrict__ matE,
    float* __restrict__ NUM_N, float* __restrict__ DEN_N,
    float* __restrict__ NUM_E, float* __restrict__ DEN_E)
{
  const int bid = blockIdx.x;
  const int tile = bid >> 2, s = bid & 3;
  const int n0 = tile * NB;
  const int h = threadIdx.x >> 6, lane = threadIdx.x & 63;

  __shared__ __align__(16) float lds_W[8][NB][64];   // 64 KiB, per-wave region
  __shared__ int   lds_mask[NB][64];                 // 8 KiB, shared
  __shared__ float lds_srcN[8][NB];
  __shared__ float lds_srcE[8][NB];

  if (lane < NB) {
    lds_srcN[h][lane] = srcN[h * N_NODES + n0 + lane];
    lds_srcE[h][lane] = srcE[h * N_NODES + n0 + lane];
  }
  __syncthreads();

  // nodes part: m in [s*512, s*512+512)
  gat_part(matN, N_NODES, tgtN, N_NODES, ht_n, lds_srcN[h], lds_W[h], lds_mask,
           n0, s * 512, s * 512 + 512, h, lane, NUM_N, DEN_N, s * 8 + h);
  // edges part: m in [s*1024, s*1024+1024)
  gat_part(matE, N_EDGES, tgtE, N_EDGES, ht_e, lds_srcE[h], lds_W[h], lds_mask,
           n0, s * 1024, s * 1024 + 1024, h, lane, NUM_E, DEN_E, s * 8 + h);
}

// ---------------------------------------------------------------------------
// Kernel 4: combine split partials, per-head normalize, mean over heads.
// ---------------------------------------------------------------------------
__global__ __launch_bounds__(256) void reduce_kernel(
    const float* __restrict__ NUM_N, const float* __restrict__ DEN_N,
    const float* __restrict__ NUM_E, const float* __restrict__ DEN_E,
    float* __restrict__ out)
{
  int idx = blockIdx.x * 256 + threadIdx.x;   // n*64 + d
  int n = idx >> 6, d = idx & 63;
  float r = 0.f;
#pragma unroll
  for (int h = 0; h < H_HEADS; ++h) {
    float nn = 0.f, dn = 0.f, ne = 0.f, de = 0.f;
#pragma unroll
    for (int s2 = 0; s2 < SPLITS; ++s2) {
      int sh = s2 * 8 + h;
      nn += NUM_N[((size_t)sh * N_NODES + n) * 64 + d];
      dn += DEN_N[(size_t)sh * N_NODES + n];
      ne += NUM_E[((size_t)sh * N_NODES + n) * 64 + d];
      de += DEN_E[(size_t)sh * N_NODES + n];
    }
    r += nn / dn + ne / de;
  }
  out[idx] = r * 0.125f;
}

// ---------------------------------------------------------------------------
extern "C" void kernel_launch(void* const* d_in, const int* in_sizes, int n_in,
                              void* d_out, int out_size, void* d_ws, size_t ws_size,
                              hipStream_t stream)
{
  const float* nodes = (const float*)d_in[0];
  const float* edges = (const float*)d_in[1];
  const float* WN    = (const float*)d_in[2];
  const float* WE    = (const float*)d_in[3];
  const float* aN    = (const float*)d_in[4];
  const float* aE    = (const float*)d_in[5];
  const int*   matN  = (const int*)d_in[6];
  const int*   matE  = (const int*)d_in[7];
  float* out = (float*)d_out;

  float* ws = (float*)d_ws;
  size_t o = 0;
  float* ht_n  = ws + o;  o += (size_t)N_NODES * HD;                    // 4 MB
  float* ht_e  = ws + o;  o += (size_t)N_EDGES * HD;                    // 8 MB
  float* srcN  = ws + o;  o += (size_t)H_HEADS * N_NODES;
  float* tgtN  = ws + o;  o += (size_t)H_HEADS * N_NODES;
  float* srcE  = ws + o;  o += (size_t)H_HEADS * N_NODES;
  float* tgtE  = ws + o;  o += (size_t)H_HEADS * N_EDGES;
  float* NUM_N = ws + o;  o += (size_t)SPLITS * H_HEADS * N_NODES * DHEAD; // 16 MB
  float* DEN_N = ws + o;  o += (size_t)SPLITS * H_HEADS * N_NODES;
  float* NUM_E = ws + o;  o += (size_t)SPLITS * H_HEADS * N_NODES * DHEAD; // 16 MB
  float* DEN_E = ws + o;  o += (size_t)SPLITS * H_HEADS * N_NODES;

  hipLaunchKernelGGL(gemm_ht, dim3(96, 8), dim3(256), 0, stream,
                     nodes, edges, WN, WE, ht_n, ht_e);
  hipLaunchKernelGGL(scores_kernel, dim3(20480), dim3(256), 0, stream,
                     ht_n, ht_e, aN, aE, srcN, tgtN, srcE, tgtE);
  hipLaunchKernelGGL(gat_main, dim3(64 * SPLITS), dim3(512), 0, stream,
                     ht_n, ht_e, srcN, tgtN, srcE, tgtE, matN, matE,
                     NUM_N, DEN_N, NUM_E, DEN_E);
  hipLaunchKernelGGL(reduce_kernel, dim3(512), dim3(256), 0, stream,
                     NUM_N, DEN_N, NUM_E, DEN_E, out);
}

// Round 2
// 143.169 us; speedup vs baseline: 3.5919x; 3.5919x over previous
//
#include <hip/hip_runtime.h>
#include <hip/hip_bf16.h>

#define N_NODES 2048
#define N_EDGES 4096
#define F_IN    256
#define H_HEADS 8
#define DHEAD   64
#define HD      512     // H_HEADS * DHEAD
#define SPLITS  4
#define NB      32      // nodes per block in main kernel

typedef __attribute__((ext_vector_type(4))) float f32x4;
typedef __attribute__((ext_vector_type(8))) short s16x8;

static __device__ __forceinline__ unsigned short f2bf(float x) {
  union { float f; unsigned u; } v; v.f = x;
  unsigned r = v.u + 0x7fff + ((v.u >> 16) & 1);   // RNE
  return (unsigned short)(r >> 16);
}

// ---------------------------------------------------------------------------
// Kernel 1: ht = X @ W (fp32 out, [m][h*64+d] layout)
// ---------------------------------------------------------------------------
__global__ __launch_bounds__(256) void gemm_ht(
    const float* __restrict__ nodes, const float* __restrict__ edges,
    const float* __restrict__ WN, const float* __restrict__ WE,
    float* __restrict__ ht_n, float* __restrict__ ht_e)
{
  const int rt = blockIdx.x;   // 96 row tiles: 0..31 nodes, 32..95 edges
  const int ct = blockIdx.y;   // 8 col tiles
  const bool isNode = (rt < 32);
  const float* __restrict__ X = isNode ? nodes : edges;
  const float* __restrict__ W = isNode ? WN : WE;
  float* __restrict__ OUT     = isNode ? ht_n : ht_e;
  const int r0 = (isNode ? rt : rt - 32) * 64;

  __shared__ __align__(16) float Xs[32][68];
  __shared__ __align__(16) float Ws[32][64];

  const int tid = threadIdx.x;
  const int tx = tid & 15, ty = tid >> 4;

  float acc[4][4];
#pragma unroll
  for (int i = 0; i < 4; ++i)
#pragma unroll
    for (int j = 0; j < 4; ++j) acc[i][j] = 0.f;

  for (int k0 = 0; k0 < F_IN; k0 += 32) {
    __syncthreads();
#pragma unroll
    for (int i = 0; i < 2; ++i) {
      int v = tid + i * 256;
      int r = v >> 3, kk = (v & 7) * 4;
      float4 x = *(const float4*)&X[(size_t)(r0 + r) * F_IN + k0 + kk];
      Xs[kk + 0][r] = x.x; Xs[kk + 1][r] = x.y;
      Xs[kk + 2][r] = x.z; Xs[kk + 3][r] = x.w;
      int kw = v >> 4, cc = (v & 15) * 4;
      *(float4*)&Ws[kw][cc] =
          *(const float4*)&W[(size_t)(k0 + kw) * HD + ct * 64 + cc];
    }
    __syncthreads();
#pragma unroll
    for (int k = 0; k < 32; ++k) {
      float4 a4 = *(const float4*)&Xs[k][ty * 4];
      float4 b4 = *(const float4*)&Ws[k][tx * 4];
      float av[4] = {a4.x, a4.y, a4.z, a4.w};
      float bv[4] = {b4.x, b4.y, b4.z, b4.w};
#pragma unroll
      for (int i = 0; i < 4; ++i)
#pragma unroll
        for (int j = 0; j < 4; ++j)
          acc[i][j] = fmaf(av[i], bv[j], acc[i][j]);
    }
  }
#pragma unroll
  for (int i = 0; i < 4; ++i) {
    float4 o = make_float4(acc[i][0], acc[i][1], acc[i][2], acc[i][3]);
    *(float4*)&OUT[(size_t)(r0 + ty * 4 + i) * HD + ct * 64 + tx * 4] = o;
  }
}

// ---------------------------------------------------------------------------
// Kernel 1b: transpose ht fp32 [m][h*64+d] -> htT bf16 [h][d][m]
// ---------------------------------------------------------------------------
__global__ __launch_bounds__(256) void transpose_ht(
    const float* __restrict__ ht_n, const float* __restrict__ ht_e,
    unsigned short* __restrict__ htT_n, unsigned short* __restrict__ htT_e)
{
  const int x = blockIdx.x, h = blockIdx.y;
  const float* src; unsigned short* dst; int M, m0;
  if (x < 32) { src = ht_n; dst = htT_n; M = N_NODES; m0 = x * 64; }
  else        { src = ht_e; dst = htT_e; M = N_EDGES; m0 = (x - 32) * 64; }

  __shared__ float T[64][65];
  const int t = threadIdx.x;
  {
    int r = t >> 2, cq = t & 3;
#pragma unroll
    for (int c4 = 0; c4 < 4; ++c4) {
      float4 v = *(const float4*)&src[(size_t)(m0 + r) * HD + h * 64 + cq * 16 + c4 * 4];
      T[r][cq * 16 + c4 * 4 + 0] = v.x;
      T[r][cq * 16 + c4 * 4 + 1] = v.y;
      T[r][cq * 16 + c4 * 4 + 2] = v.z;
      T[r][cq * 16 + c4 * 4 + 3] = v.w;
    }
  }
  __syncthreads();
  {
    int d = t >> 2, mq = t & 3;
    s16x8 o0, o1;
#pragma unroll
    for (int k = 0; k < 8; ++k) o0[k] = (short)f2bf(T[mq * 16 + k][d]);
#pragma unroll
    for (int k = 0; k < 8; ++k) o1[k] = (short)f2bf(T[mq * 16 + 8 + k][d]);
    unsigned short* p = &dst[(size_t)(h * 64 + d) * M + m0 + mq * 16];
    *(s16x8*)p = o0;
    *(s16x8*)(p + 8) = o1;
  }
}

// ---------------------------------------------------------------------------
// Kernel 2: score vectors (fp32 ht)
// ---------------------------------------------------------------------------
__global__ __launch_bounds__(256) void scores_kernel(
    const float* __restrict__ ht_n, const float* __restrict__ ht_e,
    const float* __restrict__ aN, const float* __restrict__ aE,
    float* __restrict__ srcN, float* __restrict__ tgtN,
    float* __restrict__ srcE, float* __restrict__ tgtE)
{
  int job = blockIdx.x * 4 + (threadIdx.x >> 6);
  int lane = threadIdx.x & 63;
  if (job >= 81920) return;
  const float* ht; const float* a; float* out; int h, r;
  if (job < 16384)      { int j = job;         h = j >> 11; r = j & 2047; ht = ht_n; a = aN + h * 128 + lane;      out = srcN + h * N_NODES + r; }
  else if (job < 32768) { int j = job - 16384; h = j >> 11; r = j & 2047; ht = ht_n; a = aN + h * 128 + 64 + lane; out = tgtN + h * N_NODES + r; }
  else if (job < 49152) { int j = job - 32768; h = j >> 11; r = j & 2047; ht = ht_n; a = aE + h * 128 + lane;      out = srcE + h * N_NODES + r; }
  else                  { int j = job - 49152; h = j >> 12; r = j & 4095; ht = ht_e; a = aE + h * 128 + 64 + lane; out = tgtE + h * N_EDGES + r; }
  float v = ht[(size_t)r * HD + h * 64 + lane] * (*a);
#pragma unroll
  for (int o = 32; o; o >>= 1) v += __shfl_xor(v, o);
  if (lane == 0) *out = v;
}

// ---------------------------------------------------------------------------
// Kernel 3: main GAT accumulation (MFMA).
// Per wave = head. Phase 1 (lane=m): w=mask?exp(lrelu(src+tgt)):0 in fp32,
// den accumulated in VGPRs, w packed bf16 into XOR-swizzled per-wave LDS tile.
// Phase 2: A-frags from LDS (swizzled ds_read_b128), B-frags from bf16 htT
// global (16B/lane), 16x mfma_f32_16x16x32_bf16 into fp32 acc.
// ---------------------------------------------------------------------------
__device__ __forceinline__ void gat_part_mfma(
    const int* __restrict__ mat, int mat_stride,
    const float* __restrict__ tgt_h,         // pre-offset to head h
    const float* __restrict__ src_h,         // pre-offset to head h + n0
    const unsigned short* __restrict__ htT_h,// pre-offset to head h
    int M,
    int (*lds_mask)[64], char* wbase,        // per-wave 4KB bf16 W tile
    int n0, int m_begin, int m_end, int lane, int tid,
    float* __restrict__ NUM, float* __restrict__ DEN, int sh_idx)
{
  f32x4 acc[2][4];
#pragma unroll
  for (int nt = 0; nt < 2; ++nt)
#pragma unroll
    for (int dt = 0; dt < 4; ++dt) acc[nt][dt] = (f32x4){0.f, 0.f, 0.f, 0.f};

  float den[NB];
  float srcv[NB];
#pragma unroll
  for (int n = 0; n < NB; ++n) { den[n] = 0.f; srcv[n] = src_h[n]; }

  const int q = lane >> 4, r16 = lane & 15;
  const int lane2 = lane * 2;

  for (int m0 = m_begin; m0 < m_end; m0 += 64) {
    __syncthreads();   // all waves done reading previous mask tile
    {
      int4 mv = *(const int4*)&mat[(size_t)(n0 + (tid >> 4)) * mat_stride + m0 + (tid & 15) * 4];
      *(int4*)&lds_mask[tid >> 4][(tid & 15) * 4] = mv;
    }
    __syncthreads();

    float tv = tgt_h[m0 + lane];

    // ---- phase 1: scores -> exp -> bf16 W tile (swizzled) ----
#pragma unroll
    for (int n = 0; n < NB; ++n) {
      float e = srcv[n] + tv;
      float sc = fmaxf(e, 0.f) + 0.2f * fminf(e, 0.f);
      float w = (lds_mask[n][lane] > 0) ? __expf(sc) : 0.f;
      den[n] += w;
      *(unsigned short*)(wbase + (n * 128 + (lane2 ^ ((n & 7) << 4)))) = f2bf(w);
    }

    // ---- phase 2: MFMA ----
#pragma unroll
    for (int ks = 0; ks < 2; ++ks) {
      s16x8 afr[2];
#pragma unroll
      for (int nt = 0; nt < 2; ++nt) {
        int n = nt * 16 + r16;
        afr[nt] = *(const s16x8*)(wbase + (n * 128 + ((ks * 64 + q * 16) ^ ((n & 7) << 4))));
      }
#pragma unroll
      for (int dt = 0; dt < 4; ++dt) {
        int d = dt * 16 + r16;
        s16x8 bfr = *(const s16x8*)&htT_h[(size_t)d * M + m0 + ks * 32 + q * 8];
        acc[0][dt] = __builtin_amdgcn_mfma_f32_16x16x32_bf16(afr[0], bfr, acc[0][dt], 0, 0, 0);
        acc[1][dt] = __builtin_amdgcn_mfma_f32_16x16x32_bf16(afr[1], bfr, acc[1][dt], 0, 0, 0);
      }
    }
  }

  // ---- epilogue: den reduce + stores ----
#pragma unroll
  for (int n = 0; n < NB; ++n) {
    float d = den[n];
#pragma unroll
    for (int o = 32; o; o >>= 1) d += __shfl_xor(d, o);
    if (lane == 0) DEN[(size_t)sh_idx * N_NODES + n0 + n] = d;
  }
#pragma unroll
  for (int nt = 0; nt < 2; ++nt)
#pragma unroll
    for (int dt = 0; dt < 4; ++dt)
#pragma unroll
      for (int qi = 0; qi < 4; ++qi) {
        int n = nt * 16 + (lane >> 4) * 4 + qi;
        int d = dt * 16 + (lane & 15);
        NUM[((size_t)sh_idx * N_NODES + n0 + n) * 64 + d] = acc[nt][dt][qi];
      }
}

__global__ __launch_bounds__(512, 2) void gat_main(
    const unsigned short* __restrict__ htT_n, const unsigned short* __restrict__ htT_e,
    const float* __restrict__ srcN, const float* __restrict__ tgtN,
    const float* __restrict__ srcE, const float* __restrict__ tgtE,
    const int* __restrict__ matN, const int* __restrict__ matE,
    float* __restrict__ NUM_N, float* __restrict__ DEN_N,
    float* __restrict__ NUM_E, float* __restrict__ DEN_E)
{
  // XCD swizzle: dispatch idx i -> XCD i%8 (heuristic). split s = (i>>1)&3 is
  // constant per XCD => each XCD's L2 holds one 1.5MB htT m-slice.
  const int i = blockIdx.x;
  const int tile = (i & 1) * 32 + (i >> 3);   // 0..63
  const int s = (i >> 1) & 3;                 // 0..3
  const int n0 = tile * NB;
  const int h = threadIdx.x >> 6, lane = threadIdx.x & 63;
  const int tid = threadIdx.x;

  __shared__ int lds_mask[NB][64];                               // 8 KiB shared
  __shared__ __align__(16) unsigned short lds_W[H_HEADS][NB * 64]; // 32 KiB
  char* wbase = (char*)&lds_W[h][0];

  const int sh = s * 8 + h;

  gat_part_mfma(matN, N_NODES, tgtN + (size_t)h * N_NODES,
                srcN + (size_t)h * N_NODES + n0,
                htT_n + (size_t)h * 64 * N_NODES, N_NODES,
                lds_mask, wbase, n0, s * 512, s * 512 + 512, lane, tid,
                NUM_N, DEN_N, sh);
  gat_part_mfma(matE, N_EDGES, tgtE + (size_t)h * N_EDGES,
                srcE + (size_t)h * N_NODES + n0,
                htT_e + (size_t)h * 64 * N_EDGES, N_EDGES,
                lds_mask, wbase, n0, s * 1024, s * 1024 + 1024, lane, tid,
                NUM_E, DEN_E, sh);
}

// ---------------------------------------------------------------------------
// Kernel 4: combine split partials, per-head normalize, mean over heads.
// ---------------------------------------------------------------------------
__global__ __launch_bounds__(256) void reduce_kernel(
    const float* __restrict__ NUM_N, const float* __restrict__ DEN_N,
    const float* __restrict__ NUM_E, const float* __restrict__ DEN_E,
    float* __restrict__ out)
{
  int idx = blockIdx.x * 256 + threadIdx.x;
  int n = idx >> 6, d = idx & 63;
  float r = 0.f;
#pragma unroll
  for (int h = 0; h < H_HEADS; ++h) {
    float nn = 0.f, dn = 0.f, ne = 0.f, de = 0.f;
#pragma unroll
    for (int s2 = 0; s2 < SPLITS; ++s2) {
      int sh = s2 * 8 + h;
      nn += NUM_N[((size_t)sh * N_NODES + n) * 64 + d];
      dn += DEN_N[(size_t)sh * N_NODES + n];
      ne += NUM_E[((size_t)sh * N_NODES + n) * 64 + d];
      de += DEN_E[(size_t)sh * N_NODES + n];
    }
    r += nn / dn + ne / de;
  }
  out[idx] = r * 0.125f;
}

// ---------------------------------------------------------------------------
extern "C" void kernel_launch(void* const* d_in, const int* in_sizes, int n_in,
                              void* d_out, int out_size, void* d_ws, size_t ws_size,
                              hipStream_t stream)
{
  const float* nodes = (const float*)d_in[0];
  const float* edges = (const float*)d_in[1];
  const float* WN    = (const float*)d_in[2];
  const float* WE    = (const float*)d_in[3];
  const float* aN    = (const float*)d_in[4];
  const float* aE    = (const float*)d_in[5];
  const int*   matN  = (const int*)d_in[6];
  const int*   matE  = (const int*)d_in[7];
  float* out = (float*)d_out;

  float* ws = (float*)d_ws;
  size_t o = 0;
  float* ht_n  = ws + o;  o += (size_t)N_NODES * HD;
  float* ht_e  = ws + o;  o += (size_t)N_EDGES * HD;
  unsigned short* htT_n = (unsigned short*)(ws + o); o += (size_t)H_HEADS * 64 * N_NODES / 2;
  unsigned short* htT_e = (unsigned short*)(ws + o); o += (size_t)H_HEADS * 64 * N_EDGES / 2;
  float* srcN  = ws + o;  o += (size_t)H_HEADS * N_NODES;
  float* tgtN  = ws + o;  o += (size_t)H_HEADS * N_NODES;
  float* srcE  = ws + o;  o += (size_t)H_HEADS * N_NODES;
  float* tgtE  = ws + o;  o += (size_t)H_HEADS * N_EDGES;
  float* NUM_N = ws + o;  o += (size_t)SPLITS * H_HEADS * N_NODES * DHEAD;
  float* DEN_N = ws + o;  o += (size_t)SPLITS * H_HEADS * N_NODES;
  float* NUM_E = ws + o;  o += (size_t)SPLITS * H_HEADS * N_NODES * DHEAD;
  float* DEN_E = ws + o;  o += (size_t)SPLITS * H_HEADS * N_NODES;

  hipLaunchKernelGGL(gemm_ht, dim3(96, 8), dim3(256), 0, stream,
                     nodes, edges, WN, WE, ht_n, ht_e);
  hipLaunchKernelGGL(transpose_ht, dim3(96, 8), dim3(256), 0, stream,
                     ht_n, ht_e, htT_n, htT_e);
  hipLaunchKernelGGL(scores_kernel, dim3(20480), dim3(256), 0, stream,
                     ht_n, ht_e, aN, aE, srcN, tgtN, srcE, tgtE);
  hipLaunchKernelGGL(gat_main, dim3(64 * SPLITS), dim3(512), 0, stream,
                     htT_n, htT_e, srcN, tgtN, srcE, tgtE, matN, matE,
                     NUM_N, DEN_N, NUM_E, DEN_E);
  hipLaunchKernelGGL(reduce_kernel, dim3(512), dim3(256), 0, stream,
                     NUM_N, DEN_N, NUM_E, DEN_E, out);
}

// Round 4
// 134.761 us; speedup vs baseline: 3.8160x; 1.0624x over previous
//
#include <hip/hip_runtime.h>
#include <hip/hip_bf16.h>

#define N_NODES 2048
#define N_EDGES 4096
#define F_IN    256
#define H_HEADS 8
#define HD      512
#define SPLITS  4
#define NB      32

typedef __attribute__((ext_vector_type(4))) float f32x4;
typedef __attribute__((ext_vector_type(8))) short s16x8;

static __device__ __forceinline__ unsigned short f2bf(float x) {
  union { float f; unsigned u; } v; v.f = x;
  unsigned r = v.u + 0x7fff + ((v.u >> 16) & 1);   // RNE
  return (unsigned short)(r >> 16);
}

// ---------------------------------------------------------------------------
// Kernel A: bit-pack masks along m.  bits[n][m/32], bit j = mat[n][w*32+j].
// ---------------------------------------------------------------------------
__global__ __launch_bounds__(256) void pack_masks(
    const int* __restrict__ matN, const int* __restrict__ matE,
    unsigned* __restrict__ bitsN, unsigned* __restrict__ bitsE)
{
  int t = blockIdx.x * 256 + threadIdx.x;      // 393216 threads
  const int* src; unsigned* dst;
  if (t < N_NODES * (N_NODES / 32)) {
    int row = t >> 6, w = t & 63;
    src = &matN[(size_t)row * N_NODES + w * 32]; dst = &bitsN[t];
  } else {
    int tt = t - N_NODES * (N_NODES / 32);
    int row = tt >> 7, w = tt & 127;
    src = &matE[(size_t)row * N_EDGES + w * 32]; dst = &bitsE[tt];
  }
  unsigned b = 0;
#pragma unroll
  for (int k = 7; k >= 0; --k) {
    int4 v = *(const int4*)&src[k * 4];
    b = (b << 1) | ((unsigned)v.w & 1u);
    b = (b << 1) | ((unsigned)v.z & 1u);
    b = (b << 1) | ((unsigned)v.y & 1u);
    b = (b << 1) | ((unsigned)v.x & 1u);
  }
  *dst = b;
}

// ---------------------------------------------------------------------------
// Kernel B: fused ht-GEMM + bf16 transpose-out + score vectors.
// Block (rt, ct=head): 64 rows x 64 d (one full head). No LDS aliasing.
// ---------------------------------------------------------------------------
__global__ __launch_bounds__(256) void gemm_fused(
    const float* __restrict__ nodes, const float* __restrict__ edges,
    const float* __restrict__ WN, const float* __restrict__ WE,
    const float* __restrict__ aN, const float* __restrict__ aE,
    unsigned short* __restrict__ htT_n, unsigned short* __restrict__ htT_e,
    float* __restrict__ srcN, float* __restrict__ tgtN,
    float* __restrict__ srcE, float* __restrict__ tgtE)
{
  const int rt = blockIdx.x;   // 0..31 nodes, 32..95 edges
  const int h  = blockIdx.y;   // head
  const bool isNode = (rt < 32);
  const float* __restrict__ X = isNode ? nodes : edges;
  const float* __restrict__ W = isNode ? WN : WE;
  const int r0 = (isNode ? rt : rt - 32) * 64;
  const int M  = isNode ? N_NODES : N_EDGES;

  __shared__ __align__(16) float Xs[32][68];
  __shared__ __align__(16) float Ws[32][64];
  __shared__ __align__(16) float T[64][68];    // T[d][m_local]

  const int tid = threadIdx.x;
  const int tx = tid & 15, ty = tid >> 4;

  float acc[4][4];
#pragma unroll
  for (int i = 0; i < 4; ++i)
#pragma unroll
    for (int j = 0; j < 4; ++j) acc[i][j] = 0.f;

  for (int k0 = 0; k0 < F_IN; k0 += 32) {
    __syncthreads();
#pragma unroll
    for (int i = 0; i < 2; ++i) {
      int v = tid + i * 256;
      int r = v >> 3, kk = (v & 7) * 4;
      float4 x = *(const float4*)&X[(size_t)(r0 + r) * F_IN + k0 + kk];
      Xs[kk + 0][r] = x.x; Xs[kk + 1][r] = x.y;
      Xs[kk + 2][r] = x.z; Xs[kk + 3][r] = x.w;
      int kw = v >> 4, cc = (v & 15) * 4;
      *(float4*)&Ws[kw][cc] =
          *(const float4*)&W[(size_t)(k0 + kw) * HD + h * 64 + cc];
    }
    __syncthreads();
#pragma unroll
    for (int k = 0; k < 32; ++k) {
      float4 a4 = *(const float4*)&Xs[k][ty * 4];
      float4 b4 = *(const float4*)&Ws[k][tx * 4];
      float av[4] = {a4.x, a4.y, a4.z, a4.w};
      float bv[4] = {b4.x, b4.y, b4.z, b4.w};
#pragma unroll
      for (int i = 0; i < 4; ++i)
#pragma unroll
        for (int j = 0; j < 4; ++j)
          acc[i][j] = fmaf(av[i], bv[j], acc[i][j]);
    }
  }

  // ---- epilogue: acc -> T[d][m_local] ----
  __syncthreads();
#pragma unroll
  for (int i = 0; i < 4; ++i)
#pragma unroll
    for (int j = 0; j < 4; ++j)
      T[tx * 4 + j][ty * 4 + i] = acc[i][j];
  __syncthreads();

  // bf16 transposed write: htT[h][d][m]
  {
    int d = tid >> 2, mq = tid & 3;
    s16x8 o0, o1;
#pragma unroll
    for (int k = 0; k < 8; ++k) o0[k] = (short)f2bf(T[d][mq * 16 + k]);
#pragma unroll
    for (int k = 0; k < 8; ++k) o1[k] = (short)f2bf(T[d][mq * 16 + 8 + k]);
    unsigned short* dst = isNode ? htT_n : htT_e;
    unsigned short* p = &dst[(size_t)(h * 64 + d) * M + r0 + mq * 16];
    *(s16x8*)p = o0;
    *(s16x8*)(p + 8) = o1;
  }

  // score vectors
  {
    int r = tid >> 2, q4 = tid & 3;
    float tr[16];
#pragma unroll
    for (int k = 0; k < 16; ++k) tr[k] = T[q4 * 16 + k][r];
    if (isNode) {
      float s1 = 0.f, s2 = 0.f, s3 = 0.f;
#pragma unroll
      for (int k = 0; k < 16; ++k) {
        float a1 = aN[h * 128 + q4 * 16 + k];
        float a2 = aN[h * 128 + 64 + q4 * 16 + k];
        float a3 = aE[h * 128 + q4 * 16 + k];
        s1 = fmaf(tr[k], a1, s1);
        s2 = fmaf(tr[k], a2, s2);
        s3 = fmaf(tr[k], a3, s3);
      }
      s1 += __shfl_xor(s1, 1); s1 += __shfl_xor(s1, 2);
      s2 += __shfl_xor(s2, 1); s2 += __shfl_xor(s2, 2);
      s3 += __shfl_xor(s3, 1); s3 += __shfl_xor(s3, 2);
      if (q4 == 0) {
        srcN[h * N_NODES + r0 + r] = s1;
        tgtN[h * N_NODES + r0 + r] = s2;
        srcE[h * N_NODES + r0 + r] = s3;
      }
    } else {
      float s4 = 0.f;
#pragma unroll
      for (int k = 0; k < 16; ++k)
        s4 = fmaf(tr[k], aE[h * 128 + 64 + q4 * 16 + k], s4);
      s4 += __shfl_xor(s4, 1); s4 += __shfl_xor(s4, 2);
      if (q4 == 0) tgtE[h * N_EDGES + r0 + r] = s4;
    }
  }
}

// ---------------------------------------------------------------------------
// Kernel C: main GAT accumulation — no LDS, no barriers, no unions.
// ---------------------------------------------------------------------------
struct MetaT {
  unsigned wd0a, wd0b, wd1a, wd1b;     // mask words [nt][ks]
  float4 t0a, t0b, t1a, t1b;           // tgt values [ks][half]
};

__device__ __forceinline__ MetaT load_meta(
    const unsigned* __restrict__ bits, int Wn,
    const float* __restrict__ tgt_h, int n0, int m0, int r16, int qo)
{
  MetaT mt;
  int w0 = m0 >> 5;
  mt.wd0a = bits[(size_t)(n0 + r16) * Wn + w0];
  mt.wd0b = bits[(size_t)(n0 + r16) * Wn + w0 + 1];
  mt.wd1a = bits[(size_t)(n0 + 16 + r16) * Wn + w0];
  mt.wd1b = bits[(size_t)(n0 + 16 + r16) * Wn + w0 + 1];
  mt.t0a = *(const float4*)&tgt_h[m0 + qo];
  mt.t0b = *(const float4*)&tgt_h[m0 + qo + 4];
  mt.t1a = *(const float4*)&tgt_h[m0 + 32 + qo];
  mt.t1b = *(const float4*)&tgt_h[m0 + 32 + qo + 4];
  return mt;
}

__device__ __forceinline__ void step_body(
    const MetaT& mt, const unsigned short* __restrict__ htT_h, int M, int m0,
    int r16, int qo, float src0, float src1,
    float& den0, float& den1, f32x4 acc[2][4])
{
  // B-frags (issued first; consumed after phase-1)
  s16x8 bfr[2][4];
#pragma unroll
  for (int ks = 0; ks < 2; ++ks)
#pragma unroll
    for (int dt = 0; dt < 4; ++dt)
      bfr[ks][dt] = *(const s16x8*)&htT_h[(size_t)(dt * 16 + r16) * M + m0 + ks * 32 + qo];

  // phase 1: scores -> masked exp -> A-frags (pure element-wise vector build)
  s16x8 afr[2][2];
#pragma unroll
  for (int nt = 0; nt < 2; ++nt) {
    float sn = nt ? src1 : src0;
#pragma unroll
    for (int ks = 0; ks < 2; ++ks) {
      unsigned wdw = ks ? (nt ? mt.wd1b : mt.wd0b) : (nt ? mt.wd1a : mt.wd0a);
      unsigned b8 = (wdw >> qo) & 0xffu;
      float4 ta = ks ? mt.t1a : mt.t0a;
      float4 tb = ks ? mt.t1b : mt.t0b;
      float tv[8] = {ta.x, ta.y, ta.z, ta.w, tb.x, tb.y, tb.z, tb.w};
      float wv[8];
#pragma unroll
      for (int j = 0; j < 8; ++j) {
        float e  = sn + tv[j];
        float sc = fmaxf(e, 0.2f * e);          // LeakyReLU
        float ex = __expf(sc);
        wv[j] = ((b8 >> j) & 1u) ? ex : 0.f;
      }
      float dsum = ((wv[0] + wv[1]) + (wv[2] + wv[3])) +
                   ((wv[4] + wv[5]) + (wv[6] + wv[7]));
      if (nt) den1 += dsum; else den0 += dsum;
#pragma unroll
      for (int j = 0; j < 8; ++j)
        afr[nt][ks][j] = (short)f2bf(wv[j]);
    }
  }

  // phase 2: MFMA
#pragma unroll
  for (int ks = 0; ks < 2; ++ks)
#pragma unroll
    for (int dt = 0; dt < 4; ++dt) {
      acc[0][dt] = __builtin_amdgcn_mfma_f32_16x16x32_bf16(afr[0][ks], bfr[ks][dt], acc[0][dt], 0, 0, 0);
      acc[1][dt] = __builtin_amdgcn_mfma_f32_16x16x32_bf16(afr[1][ks], bfr[ks][dt], acc[1][dt], 0, 0, 0);
    }
}

__device__ void gat_part_v3(
    const unsigned* __restrict__ bits, int Wn,
    const float* __restrict__ tgt_h, const float* __restrict__ src_h,  // src pre-offset +n0
    const unsigned short* __restrict__ htT_h, int M,
    int n0, int m_begin, int nsteps, int lane,
    float* __restrict__ NUM, float* __restrict__ DEN, int sh)
{
  const int r16 = lane & 15, q = lane >> 4, qo = q * 8;
  f32x4 acc[2][4];
#pragma unroll
  for (int nt = 0; nt < 2; ++nt)
#pragma unroll
    for (int dt = 0; dt < 4; ++dt) acc[nt][dt] = (f32x4){0.f, 0.f, 0.f, 0.f};
  float den0 = 0.f, den1 = 0.f;
  float src0 = src_h[r16], src1 = src_h[16 + r16];

  MetaT A = load_meta(bits, Wn, tgt_h, n0, m_begin, r16, qo);
  for (int s2 = 0; s2 < nsteps; s2 += 2) {           // nsteps is even
    int m0 = m_begin + s2 * 64;
    MetaT B = load_meta(bits, Wn, tgt_h, n0, m0 + 64, r16, qo);
    step_body(A, htT_h, M, m0, r16, qo, src0, src1, den0, den1, acc);
    A = load_meta(bits, Wn, tgt_h, n0,
                  (s2 + 2 < nsteps) ? m0 + 128 : m_begin, r16, qo);
    step_body(B, htT_h, M, m0 + 64, r16, qo, src0, src1, den0, den1, acc);
  }

  den0 += __shfl_xor(den0, 16); den0 += __shfl_xor(den0, 32);
  den1 += __shfl_xor(den1, 16); den1 += __shfl_xor(den1, 32);
  if (q == 0) {
    DEN[(size_t)sh * N_NODES + n0 + r16] = den0;
    DEN[(size_t)sh * N_NODES + n0 + 16 + r16] = den1;
  }
#pragma unroll
  for (int nt = 0; nt < 2; ++nt)
#pragma unroll
    for (int dt = 0; dt < 4; ++dt)
#pragma unroll
      for (int qi = 0; qi < 4; ++qi) {
        int n = nt * 16 + q * 4 + qi;
        int d = dt * 16 + r16;
        NUM[((size_t)sh * N_NODES + n0 + n) * 64 + d] = acc[nt][dt][qi];
      }
}

__global__ __launch_bounds__(512, 2) void gat_main(
    const unsigned short* __restrict__ htT_n, const unsigned short* __restrict__ htT_e,
    const float* __restrict__ srcN, const float* __restrict__ tgtN,
    const float* __restrict__ srcE, const float* __restrict__ tgtE,
    const unsigned* __restrict__ bitsN, const unsigned* __restrict__ bitsE,
    float* __restrict__ NUM_N, float* __restrict__ DEN_N,
    float* __restrict__ NUM_E, float* __restrict__ DEN_E)
{
  const int i = blockIdx.x;
  const int tile = (i & 1) * 32 + (i >> 3);   // XCD i%8 sees a single split s
  const int s = (i >> 1) & 3;
  const int n0 = tile * NB;
  const int h = threadIdx.x >> 6, lane = threadIdx.x & 63;
  const int sh = s * 8 + h;

  gat_part_v3(bitsN, N_NODES / 32, tgtN + (size_t)h * N_NODES,
              srcN + (size_t)h * N_NODES + n0,
              htT_n + (size_t)h * 64 * N_NODES, N_NODES,
              n0, s * 512, 8, lane, NUM_N, DEN_N, sh);
  gat_part_v3(bitsE, N_EDGES / 32, tgtE + (size_t)h * N_EDGES,
              srcE + (size_t)h * N_NODES + n0,
              htT_e + (size_t)h * 64 * N_EDGES, N_EDGES,
              n0, s * 1024, 16, lane, NUM_E, DEN_E, sh);
}

// ---------------------------------------------------------------------------
// Kernel D: combine split partials, normalize, mean over heads.
// ---------------------------------------------------------------------------
__global__ __launch_bounds__(256) void reduce_kernel(
    const float* __restrict__ NUM_N, const float* __restrict__ DEN_N,
    const float* __restrict__ NUM_E, const float* __restrict__ DEN_E,
    float* __restrict__ out)
{
  int idx = blockIdx.x * 256 + threadIdx.x;
  int n = idx >> 6, d = idx & 63;
  float r = 0.f;
#pragma unroll
  for (int h = 0; h < H_HEADS; ++h) {
    float nn = 0.f, dn = 0.f, ne = 0.f, de = 0.f;
#pragma unroll
    for (int s2 = 0; s2 < SPLITS; ++s2) {
      int sh = s2 * 8 + h;
      nn += NUM_N[((size_t)sh * N_NODES + n) * 64 + d];
      dn += DEN_N[(size_t)sh * N_NODES + n];
      ne += NUM_E[((size_t)sh * N_NODES + n) * 64 + d];
      de += DEN_E[(size_t)sh * N_NODES + n];
    }
    r += nn / dn + ne / de;
  }
  out[idx] = r * 0.125f;
}

// ---------------------------------------------------------------------------
extern "C" void kernel_launch(void* const* d_in, const int* in_sizes, int n_in,
                              void* d_out, int out_size, void* d_ws, size_t ws_size,
                              hipStream_t stream)
{
  const float* nodes = (const float*)d_in[0];
  const float* edges = (const float*)d_in[1];
  const float* WN    = (const float*)d_in[2];
  const float* WE    = (const float*)d_in[3];
  const float* aN    = (const float*)d_in[4];
  const float* aE    = (const float*)d_in[5];
  const int*   matN  = (const int*)d_in[6];
  const int*   matE  = (const int*)d_in[7];
  float* out = (float*)d_out;

  float* ws = (float*)d_ws;
  size_t o = 0;
  unsigned short* htT_n = (unsigned short*)(ws + o); o += (size_t)H_HEADS * 64 * N_NODES / 2;  // 2MB
  unsigned short* htT_e = (unsigned short*)(ws + o); o += (size_t)H_HEADS * 64 * N_EDGES / 2;  // 4MB
  unsigned* bitsN = (unsigned*)(ws + o); o += (size_t)N_NODES * (N_NODES / 32);                // 512KB
  unsigned* bitsE = (unsigned*)(ws + o); o += (size_t)N_NODES * (N_EDGES / 32);                // 1MB
  float* srcN  = ws + o;  o += (size_t)H_HEADS * N_NODES;
  float* tgtN  = ws + o;  o += (size_t)H_HEADS * N_NODES;
  float* srcE  = ws + o;  o += (size_t)H_HEADS * N_NODES;
  float* tgtE  = ws + o;  o += (size_t)H_HEADS * N_EDGES;
  float* NUM_N = ws + o;  o += (size_t)SPLITS * H_HEADS * N_NODES * 64;   // 16MB
  float* DEN_N = ws + o;  o += (size_t)SPLITS * H_HEADS * N_NODES;
  float* NUM_E = ws + o;  o += (size_t)SPLITS * H_HEADS * N_NODES * 64;   // 16MB
  float* DEN_E = ws + o;  o += (size_t)SPLITS * H_HEADS * N_NODES;

  hipLaunchKernelGGL(pack_masks, dim3(1536), dim3(256), 0, stream,
                     matN, matE, bitsN, bitsE);
  hipLaunchKernelGGL(gemm_fused, dim3(96, 8), dim3(256), 0, stream,
                     nodes, edges, WN, WE, aN, aE,
                     htT_n, htT_e, srcN, tgtN, srcE, tgtE);
  hipLaunchKernelGGL(gat_main, dim3(64 * SPLITS), dim3(512), 0, stream,
                     htT_n, htT_e, srcN, tgtN, srcE, tgtE, bitsN, bitsE,
                     NUM_N, DEN_N, NUM_E, DEN_E);
  hipLaunchKernelGGL(reduce_kernel, dim3(512), dim3(256), 0, stream,
                     NUM_N, DEN_N, NUM_E, DEN_E, out);
}

// Round 6
// 123.206 us; speedup vs baseline: 4.1739x; 1.0938x over previous
//
#include <hip/hip_runtime.h>
#include <hip/hip_bf16.h>

#define N_NODES 2048
#define N_EDGES 4096
#define F_IN    256
#define H_HEADS 8
#define HD      512

typedef __attribute__((ext_vector_type(4))) float f32x4;
typedef __attribute__((ext_vector_type(8))) short s16x8;
typedef __attribute__((ext_vector_type(4))) unsigned u32x4;

static __device__ __forceinline__ unsigned short f2bf(float x) {
  union { float f; unsigned u; } v; v.f = x;
  unsigned r = v.u + 0x7fff + ((v.u >> 16) & 1);   // RNE
  return (unsigned short)(r >> 16);
}
// round-half-up bf16 pack of two floats -> one u32 (lo | hi<<16)
// lo bf16 = (ua+0x8000)>>16 ; hi bf16 in top half = (ub+0x8000)&0xffff0000
static __device__ __forceinline__ unsigned bfpack2(float lo, float hi) {
  unsigned ua = __float_as_uint(lo) + 0x8000u;
  unsigned ub = __float_as_uint(hi) + 0x8000u;
  return (ua >> 16) | (ub & 0xffff0000u);
}

// ---------------------------------------------------------------------------
// Kernel A: bit-pack masks along m.  bits[n][m/32], bit j = mat[n][w*32+j].
// ---------------------------------------------------------------------------
__global__ __launch_bounds__(256) void pack_masks(
    const int* __restrict__ matN, const int* __restrict__ matE,
    unsigned* __restrict__ bitsN, unsigned* __restrict__ bitsE)
{
  int t = blockIdx.x * 256 + threadIdx.x;      // 393216 threads
  const int* src; unsigned* dst;
  if (t < N_NODES * (N_NODES / 32)) {
    int row = t >> 6, w = t & 63;
    src = &matN[(size_t)row * N_NODES + w * 32]; dst = &bitsN[t];
  } else {
    int tt = t - N_NODES * (N_NODES / 32);
    int row = tt >> 7, w = tt & 127;
    src = &matE[(size_t)row * N_EDGES + w * 32]; dst = &bitsE[tt];
  }
  unsigned b = 0;
#pragma unroll
  for (int k = 7; k >= 0; --k) {
    int4 v = *(const int4*)&src[k * 4];
    b = (b << 1) | ((unsigned)v.w & 1u);
    b = (b << 1) | ((unsigned)v.z & 1u);
    b = (b << 1) | ((unsigned)v.y & 1u);
    b = (b << 1) | ((unsigned)v.x & 1u);
  }
  *dst = b;
}

// ---------------------------------------------------------------------------
// Kernel B: fused ht-GEMM + bf16 transpose-out + score vectors.
// ---------------------------------------------------------------------------
__global__ __launch_bounds__(256) void gemm_fused(
    const float* __restrict__ nodes, const float* __restrict__ edges,
    const float* __restrict__ WN, const float* __restrict__ WE,
    const float* __restrict__ aN, const float* __restrict__ aE,
    unsigned short* __restrict__ htT_n, unsigned short* __restrict__ htT_e,
    float* __restrict__ srcN, float* __restrict__ tgtN,
    float* __restrict__ srcE, float* __restrict__ tgtE)
{
  const int rt = blockIdx.x;   // 0..31 nodes, 32..95 edges
  const int h  = blockIdx.y;   // head
  const bool isNode = (rt < 32);
  const float* __restrict__ X = isNode ? nodes : edges;
  const float* __restrict__ W = isNode ? WN : WE;
  const int r0 = (isNode ? rt : rt - 32) * 64;
  const int M  = isNode ? N_NODES : N_EDGES;

  __shared__ __align__(16) float Xs[32][68];
  __shared__ __align__(16) float Ws[32][64];
  __shared__ __align__(16) float T[64][68];    // T[d][m_local]

  const int tid = threadIdx.x;
  const int tx = tid & 15, ty = tid >> 4;

  float acc[4][4];
#pragma unroll
  for (int i = 0; i < 4; ++i)
#pragma unroll
    for (int j = 0; j < 4; ++j) acc[i][j] = 0.f;

  for (int k0 = 0; k0 < F_IN; k0 += 32) {
    __syncthreads();
#pragma unroll
    for (int i = 0; i < 2; ++i) {
      int v = tid + i * 256;
      int r = v >> 3, kk = (v & 7) * 4;
      float4 x = *(const float4*)&X[(size_t)(r0 + r) * F_IN + k0 + kk];
      Xs[kk + 0][r] = x.x; Xs[kk + 1][r] = x.y;
      Xs[kk + 2][r] = x.z; Xs[kk + 3][r] = x.w;
      int kw = v >> 4, cc = (v & 15) * 4;
      *(float4*)&Ws[kw][cc] =
          *(const float4*)&W[(size_t)(k0 + kw) * HD + h * 64 + cc];
    }
    __syncthreads();
#pragma unroll
    for (int k = 0; k < 32; ++k) {
      float4 a4 = *(const float4*)&Xs[k][ty * 4];
      float4 b4 = *(const float4*)&Ws[k][tx * 4];
      float av[4] = {a4.x, a4.y, a4.z, a4.w};
      float bv[4] = {b4.x, b4.y, b4.z, b4.w};
#pragma unroll
      for (int i = 0; i < 4; ++i)
#pragma unroll
        for (int j = 0; j < 4; ++j)
          acc[i][j] = fmaf(av[i], bv[j], acc[i][j]);
    }
  }

  __syncthreads();
#pragma unroll
  for (int i = 0; i < 4; ++i)
#pragma unroll
    for (int j = 0; j < 4; ++j)
      T[tx * 4 + j][ty * 4 + i] = acc[i][j];
  __syncthreads();

  // bf16 transposed write: htT[h][d][m]
  {
    int d = tid >> 2, mq = tid & 3;
    s16x8 o0, o1;
#pragma unroll
    for (int k = 0; k < 8; ++k) o0[k] = (short)f2bf(T[d][mq * 16 + k]);
#pragma unroll
    for (int k = 0; k < 8; ++k) o1[k] = (short)f2bf(T[d][mq * 16 + 8 + k]);
    unsigned short* dst = isNode ? htT_n : htT_e;
    unsigned short* p = &dst[(size_t)(h * 64 + d) * M + r0 + mq * 16];
    *(s16x8*)p = o0;
    *(s16x8*)(p + 8) = o1;
  }

  // score vectors
  {
    int r = tid >> 2, q4 = tid & 3;
    float tr[16];
#pragma unroll
    for (int k = 0; k < 16; ++k) tr[k] = T[q4 * 16 + k][r];
    if (isNode) {
      float s1 = 0.f, s2 = 0.f, s3 = 0.f;
#pragma unroll
      for (int k = 0; k < 16; ++k) {
        s1 = fmaf(tr[k], aN[h * 128 + q4 * 16 + k], s1);
        s2 = fmaf(tr[k], aN[h * 128 + 64 + q4 * 16 + k], s2);
        s3 = fmaf(tr[k], aE[h * 128 + q4 * 16 + k], s3);
      }
      s1 += __shfl_xor(s1, 1); s1 += __shfl_xor(s1, 2);
      s2 += __shfl_xor(s2, 1); s2 += __shfl_xor(s2, 2);
      s3 += __shfl_xor(s3, 1); s3 += __shfl_xor(s3, 2);
      if (q4 == 0) {
        srcN[h * N_NODES + r0 + r] = s1;
        tgtN[h * N_NODES + r0 + r] = s2;
        srcE[h * N_NODES + r0 + r] = s3;
      }
    } else {
      float s4 = 0.f;
#pragma unroll
      for (int k = 0; k < 16; ++k)
        s4 = fmaf(tr[k], aE[h * 128 + 64 + q4 * 16 + k], s4);
      s4 += __shfl_xor(s4, 1); s4 += __shfl_xor(s4, 2);
      if (q4 == 0) tgtE[h * N_EDGES + r0 + r] = s4;
    }
  }
}

// ---------------------------------------------------------------------------
// Kernel C: main GAT. Block = (32-node tile, head), 8 waves; wave w owns
// m-slice w. Den via ones-column MFMA. In-block LDS combine + normalize.
// ---------------------------------------------------------------------------
__device__ __forceinline__ void gat_part(
    const unsigned* __restrict__ bits, int Wn,
    const float* __restrict__ tgt_h,
    const unsigned short* __restrict__ htT_h, int M,
    int n0, int m_begin, int nsteps, int r16, int qo,
    float src0, float src1, s16x8 ones,
    f32x4 acc[2][4], f32x4 accd[2])
{
#pragma unroll
  for (int nt = 0; nt < 2; ++nt) {
    accd[nt] = (f32x4){0.f, 0.f, 0.f, 0.f};
#pragma unroll
    for (int dt = 0; dt < 4; ++dt) acc[nt][dt] = (f32x4){0.f, 0.f, 0.f, 0.f};
  }
  const unsigned* brow0 = &bits[(size_t)(n0 + r16) * Wn];
  const unsigned* brow1 = &bits[(size_t)(n0 + 16 + r16) * Wn];

  for (int st = 0; st < nsteps; ++st) {
    int m0 = m_begin + st * 64;
    int w0 = m0 >> 5;
    unsigned wd00 = brow0[w0], wd01 = brow0[w0 + 1];
    unsigned wd10 = brow1[w0], wd11 = brow1[w0 + 1];
    float4 t00 = *(const float4*)&tgt_h[m0 + qo];
    float4 t01 = *(const float4*)&tgt_h[m0 + qo + 4];
    float4 t10 = *(const float4*)&tgt_h[m0 + 32 + qo];
    float4 t11 = *(const float4*)&tgt_h[m0 + 32 + qo + 4];

    s16x8 bfr[2][4];
#pragma unroll
    for (int ks = 0; ks < 2; ++ks)
#pragma unroll
      for (int dt = 0; dt < 4; ++dt)
        bfr[ks][dt] = *(const s16x8*)&htT_h[(size_t)(dt * 16 + r16) * M + m0 + ks * 32 + qo];

    s16x8 afr[2][2];
#pragma unroll
    for (int nt = 0; nt < 2; ++nt) {
      float sn = nt ? src1 : src0;
#pragma unroll
      for (int ks = 0; ks < 2; ++ks) {
        unsigned wdw = nt ? (ks ? wd11 : wd10) : (ks ? wd01 : wd00);
        unsigned b8 = (wdw >> qo) & 0xffu;
        float4 ta = ks ? t10 : t00;
        float4 tb = ks ? t11 : t01;
        float tv[8] = {ta.x, ta.y, ta.z, ta.w, tb.x, tb.y, tb.z, tb.w};
        float wv[8];
#pragma unroll
        for (int j = 0; j < 8; ++j) {
          float e  = sn + tv[j];
          float sc = fmaxf(e, 0.2f * e);          // LeakyReLU
          float ex = __expf(sc);
          wv[j] = ((b8 >> j) & 1u) ? ex : 0.f;
        }
        u32x4 p;
#pragma unroll
        for (int jp = 0; jp < 4; ++jp)
          p[jp] = bfpack2(wv[2 * jp], wv[2 * jp + 1]);
        afr[nt][ks] = __builtin_bit_cast(s16x8, p);
      }
    }

#pragma unroll
    for (int ks = 0; ks < 2; ++ks) {
#pragma unroll
      for (int dt = 0; dt < 4; ++dt) {
        acc[0][dt] = __builtin_amdgcn_mfma_f32_16x16x32_bf16(afr[0][ks], bfr[ks][dt], acc[0][dt], 0, 0, 0);
        acc[1][dt] = __builtin_amdgcn_mfma_f32_16x16x32_bf16(afr[1][ks], bfr[ks][dt], acc[1][dt], 0, 0, 0);
      }
      accd[0] = __builtin_amdgcn_mfma_f32_16x16x32_bf16(afr[0][ks], ones, accd[0], 0, 0, 0);
      accd[1] = __builtin_amdgcn_mfma_f32_16x16x32_bf16(afr[1][ks], ones, accd[1], 0, 0, 0);
    }
  }
}

__global__ __launch_bounds__(512, 4) void gat_main(
    const unsigned short* __restrict__ htT_n, const unsigned short* __restrict__ htT_e,
    const float* __restrict__ srcN, const float* __restrict__ tgtN,
    const float* __restrict__ srcE, const float* __restrict__ tgtE,
    const unsigned* __restrict__ bitsN, const unsigned* __restrict__ bitsE,
    float* __restrict__ OUTH)
{
  const int i = blockIdx.x;
  const int h = i & 7, tile = i >> 3;          // head per XCD (i%8 heuristic)
  const int n0 = tile * 32;
  const int tid = threadIdx.x, w = tid >> 6, lane = tid & 63;
  const int r16 = lane & 15, q = lane >> 4, qo = q * 8;

  __shared__ __align__(16) float lnum[H_HEADS][32][64];   // 64 KiB
  __shared__ float lden[H_HEADS][32];                     // 1 KiB

  s16x8 ones;
#pragma unroll
  for (int j = 0; j < 8; ++j) ones[j] = (short)0x3F80;    // bf16 1.0

  f32x4 acc[2][4], accd[2];
  const int cn = tid >> 4, cd4 = (tid & 15) * 4;          // combine assignment
  f32x4 r1;

  // ---------------- nodes part ----------------
  {
    float s0 = srcN[h * N_NODES + n0 + r16];
    float s1 = srcN[h * N_NODES + n0 + 16 + r16];
    gat_part(bitsN, N_NODES / 32, tgtN + (size_t)h * N_NODES,
             htT_n + (size_t)h * 64 * N_NODES, N_NODES,
             n0, w * 256, 4, r16, qo, s0, s1, ones, acc, accd);
#pragma unroll
    for (int nt = 0; nt < 2; ++nt)
#pragma unroll
      for (int dt = 0; dt < 4; ++dt)
#pragma unroll
        for (int qi = 0; qi < 4; ++qi)
          lnum[w][nt * 16 + q * 4 + qi][dt * 16 + r16] = acc[nt][dt][qi];
    if (r16 == 0) {
#pragma unroll
      for (int nt = 0; nt < 2; ++nt)
#pragma unroll
        for (int qi = 0; qi < 4; ++qi)
          lden[w][nt * 16 + q * 4 + qi] = accd[nt][qi];
    }
    __syncthreads();
    f32x4 s = (f32x4){0.f, 0.f, 0.f, 0.f};
    float dsum = 0.f;
#pragma unroll
    for (int ww = 0; ww < 8; ++ww) {
      s += *(const f32x4*)&lnum[ww][cn][cd4];
      dsum += lden[ww][cn];
    }
    float inv = 1.0f / dsum;
    r1 = (f32x4){s.x * inv, s.y * inv, s.z * inv, s.w * inv};
    __syncthreads();   // done reading LDS before part 2 overwrites
  }

  // ---------------- edges part ----------------
  {
    float s0 = srcE[h * N_NODES + n0 + r16];
    float s1 = srcE[h * N_NODES + n0 + 16 + r16];
    gat_part(bitsE, N_EDGES / 32, tgtE + (size_t)h * N_EDGES,
             htT_e + (size_t)h * 64 * N_EDGES, N_EDGES,
             n0, w * 512, 8, r16, qo, s0, s1, ones, acc, accd);
#pragma unroll
    for (int nt = 0; nt < 2; ++nt)
#pragma unroll
      for (int dt = 0; dt < 4; ++dt)
#pragma unroll
        for (int qi = 0; qi < 4; ++qi)
          lnum[w][nt * 16 + q * 4 + qi][dt * 16 + r16] = acc[nt][dt][qi];
    if (r16 == 0) {
#pragma unroll
      for (int nt = 0; nt < 2; ++nt)
#pragma unroll
        for (int qi = 0; qi < 4; ++qi)
          lden[w][nt * 16 + q * 4 + qi] = accd[nt][qi];
    }
    __syncthreads();
    f32x4 s = (f32x4){0.f, 0.f, 0.f, 0.f};
    float dsum = 0.f;
#pragma unroll
    for (int ww = 0; ww < 8; ++ww) {
      s += *(const f32x4*)&lnum[ww][cn][cd4];
      dsum += lden[ww][cn];
    }
    float inv = 1.0f / dsum;
    f32x4 o;
    o.x = (r1.x + s.x * inv) * 0.125f;
    o.y = (r1.y + s.y * inv) * 0.125f;
    o.z = (r1.z + s.z * inv) * 0.125f;
    o.w = (r1.w + s.w * inv) * 0.125f;
    *(f32x4*)&OUTH[((size_t)h * N_NODES + n0 + cn) * 64 + cd4] = o;
  }
}

// ---------------------------------------------------------------------------
// Kernel D: out = sum over heads of OUTH (already normalized & /8).
// ---------------------------------------------------------------------------
__global__ __launch_bounds__(256) void reduce_out(
    const float* __restrict__ OUTH, float* __restrict__ out)
{
  int idx = (blockIdx.x * 256 + threadIdx.x) * 4;   // 128 blocks cover 128K elems
  f32x4 s = *(const f32x4*)&OUTH[idx];
#pragma unroll
  for (int h = 1; h < H_HEADS; ++h)
    s += *(const f32x4*)&OUTH[(size_t)h * N_NODES * 64 + idx];
  *(f32x4*)&out[idx] = s;
}

// ---------------------------------------------------------------------------
extern "C" void kernel_launch(void* const* d_in, const int* in_sizes, int n_in,
                              void* d_out, int out_size, void* d_ws, size_t ws_size,
                              hipStream_t stream)
{
  const float* nodes = (const float*)d_in[0];
  const float* edges = (const float*)d_in[1];
  const float* WN    = (const float*)d_in[2];
  const float* WE    = (const float*)d_in[3];
  const float* aN    = (const float*)d_in[4];
  const float* aE    = (const float*)d_in[5];
  const int*   matN  = (const int*)d_in[6];
  const int*   matE  = (const int*)d_in[7];
  float* out = (float*)d_out;

  float* ws = (float*)d_ws;
  size_t o = 0;
  unsigned short* htT_n = (unsigned short*)(ws + o); o += (size_t)H_HEADS * 64 * N_NODES / 2;  // 2MB
  unsigned short* htT_e = (unsigned short*)(ws + o); o += (size_t)H_HEADS * 64 * N_EDGES / 2;  // 4MB
  unsigned* bitsN = (unsigned*)(ws + o); o += (size_t)N_NODES * (N_NODES / 32);                // 512KB
  unsigned* bitsE = (unsigned*)(ws + o); o += (size_t)N_NODES * (N_EDGES / 32);                // 1MB
  float* srcN  = ws + o;  o += (size_t)H_HEADS * N_NODES;
  float* tgtN  = ws + o;  o += (size_t)H_HEADS * N_NODES;
  float* srcE  = ws + o;  o += (size_t)H_HEADS * N_NODES;
  float* tgtE  = ws + o;  o += (size_t)H_HEADS * N_EDGES;
  float* OUTH  = ws + o;  o += (size_t)H_HEADS * N_NODES * 64;                                 // 4MB

  hipLaunchKernelGGL(pack_masks, dim3(1536), dim3(256), 0, stream,
                     matN, matE, bitsN, bitsE);
  hipLaunchKernelGGL(gemm_fused, dim3(96, 8), dim3(256), 0, stream,
                     nodes, edges, WN, WE, aN, aE,
                     htT_n, htT_e, srcN, tgtN, srcE, tgtE);
  hipLaunchKernelGGL(gat_main, dim3(512), dim3(512), 0, stream,
                     htT_n, htT_e, srcN, tgtN, srcE, tgtE, bitsN, bitsE, OUTH);
  hipLaunchKernelGGL(reduce_out, dim3(128), dim3(256), 0, stream,
                     OUTH, out);
}